// Round 11
// baseline (31.882 us; speedup 1.0000x reference)
//
#include <hip/hip_runtime.h>

typedef __attribute__((ext_vector_type(8))) short short8;
typedef __attribute__((ext_vector_type(4))) float f32x4;

#define C_COUPLING 1.0f
#define TPITCH 2056   // shorts per T row: 2048 + 8 pad (4112 B)
#define SB0() __builtin_amdgcn_sched_barrier(0)

// float -> bf16 bits (round-to-nearest-ish; inputs finite, |v|<=1)
__device__ __forceinline__ unsigned short f2bf(float f) {
  unsigned u = __builtin_bit_cast(unsigned, f);
  return (unsigned short)((u + 0x8000u) >> 16);
}

__device__ __forceinline__ void step(const float4& a0, const float4& a1,
                                     const float4& l0, const float4& l1,
                                     const short8 bf, f32x4& P, f32x4& Q) {
  const float av[8] = {a0.x, a0.y, a0.z, a0.w, a1.x, a1.y, a1.z, a1.w};
  const float lv[8] = {l0.x, l0.y, l0.z, l0.w, l1.x, l1.y, l1.z, l1.w};
  short8 wc, ws;
  #pragma unroll
  for (int k = 0; k < 8; ++k) {
    const float sv = __sinf(lv[k]);
    const float cv = __cosf(lv[k]);
    wc[k] = (short)f2bf(av[k] * cv);
    ws[k] = (short)f2bf(av[k] * sv);
  }
  P = __builtin_amdgcn_mfma_f32_16x16x32_bf16(wc, bf, P, 0, 0, 0);
  Q = __builtin_amdgcn_mfma_f32_16x16x32_bf16(ws, bf, Q, 0, 0, 0);
}

// One block = (b, 16 i-rows). 8 waves = 8 j-chunks of N/8.
// LDS trig table T[c][j] (c<8: sin(theta[b,j,c]); c>=8: cos), full N width.
// P = (A.*cos(alpha)) x [sin|cos], Q = (A.*sin(alpha)) x [sin|cos].
// coupling(i,d) = c_i*(P[d]-Q[d+8]) - s_i*(P[d+8]+Q[d])
// out = gamma + (C/N)*coupling   (theta + DT*ATTR*(gamma-theta) == gamma)
__global__ __launch_bounds__(512, 4) void vk_fused(
    const float* __restrict__ theta,
    const float* __restrict__ gamma,
    const float* __restrict__ affinity,
    const float* __restrict__ alpha,
    float* __restrict__ out,
    int N) {
  __shared__ __align__(16) unsigned short T[16 * TPITCH];   // 65792 B

  const int nit = N >> 4;
  const int itile = blockIdx.x % nit;
  const int b = blockIdx.x / nit;
  const int i0 = itile << 4;

  const int tid = threadIdx.x;
  const int wave = tid >> 6, lane = tid & 63;
  const int g = lane >> 4, col = lane & 15;

  const int jch = N >> 3;
  const int j0w = wave * jch;
  const int o = g * 8;
  const float* __restrict__ Arow =
      affinity + ((size_t)b * N + i0 + col) * (size_t)N + j0w;
  const float* __restrict__ Lrow =
      alpha    + ((size_t)b * N + i0 + col) * (size_t)N + j0w;

  // ---- prefetch tiles 0,1 of this wave's j-chunk BEFORE the table build:
  //      the compulsory A/alpha stream starts at cycle ~0 and the build
  //      hides under its latency ----
  const float4 pa00 = *(const float4*)(Arow + o);
  const float4 pa01 = *(const float4*)(Arow + o + 4);
  const float4 pl00 = *(const float4*)(Lrow + o);
  const float4 pl01 = *(const float4*)(Lrow + o + 4);
  const float4 pa10 = *(const float4*)(Arow + 32 + o);
  const float4 pa11 = *(const float4*)(Arow + 32 + o + 4);
  const float4 pl10 = *(const float4*)(Lrow + 32 + o);
  const float4 pl11 = *(const float4*)(Lrow + 32 + o + 4);
  SB0();

  // ---- wave 0: epilogue operands issued early too ----
  const size_t obase = (((size_t)b * N + i0 + g * 4) << 3) + col;
  float tl[4], gv[4];
  if (wave == 0 && col < 8) {
    #pragma unroll
    for (int r = 0; r < 4; ++r) {
      tl[r] = theta[obase + 8 * r];
      gv[r] = gamma[obase + 8 * r];
    }
  }
  SB0();

  // ---- build trig table (4 consecutive j per thread per trip) ----
  {
    const int nj4 = N >> 2;
    for (int j4 = tid; j4 < nj4; j4 += 512) {
      const float* tp = theta + ((size_t)b * N + 4 * (size_t)j4) * 8;
      float v[4][8];
      #pragma unroll
      for (int jj = 0; jj < 4; ++jj) {
        const float4 x = *(const float4*)(tp + jj * 8);
        const float4 y = *(const float4*)(tp + jj * 8 + 4);
        v[jj][0] = x.x; v[jj][1] = x.y; v[jj][2] = x.z; v[jj][3] = x.w;
        v[jj][4] = y.x; v[jj][5] = y.y; v[jj][6] = y.z; v[jj][7] = y.w;
      }
      #pragma unroll
      for (int d = 0; d < 8; ++d) {
        const unsigned s0 = (unsigned)f2bf(__sinf(v[0][d])) |
                            ((unsigned)f2bf(__sinf(v[1][d])) << 16);
        const unsigned s1 = (unsigned)f2bf(__sinf(v[2][d])) |
                            ((unsigned)f2bf(__sinf(v[3][d])) << 16);
        const unsigned c0 = (unsigned)f2bf(__cosf(v[0][d])) |
                            ((unsigned)f2bf(__cosf(v[1][d])) << 16);
        const unsigned c1 = (unsigned)f2bf(__cosf(v[2][d])) |
                            ((unsigned)f2bf(__cosf(v[3][d])) << 16);
        *(uint2*)&T[d * TPITCH + 4 * j4]       = make_uint2(s0, s1);
        *(uint2*)&T[(8 + d) * TPITCH + 4 * j4] = make_uint2(c0, c1);
      }
    }
  }
  __syncthreads();

  f32x4 P = {0.f, 0.f, 0.f, 0.f};
  f32x4 Q = {0.f, 0.f, 0.f, 0.f};
  const unsigned short* Trow = T + col * TPITCH + j0w;

  // ---- peeled tiles 0,1 from the prefetched registers ----
  step(pa00, pa01, pl00, pl01, *(const short8*)(Trow + o), P, Q);
  step(pa10, pa11, pl10, pl11, *(const short8*)(Trow + 32 + o), P, Q);

  // ---- main loop over remaining tiles ----
  #pragma unroll 4
  for (int jt = 64; jt < jch; jt += 32) {
    const float4 a0 = *(const float4*)(Arow + jt + o);
    const float4 a1 = *(const float4*)(Arow + jt + o + 4);
    const float4 l0 = *(const float4*)(Lrow + jt + o);
    const float4 l1 = *(const float4*)(Lrow + jt + o + 4);
    const short8 bf = *(const short8*)(Trow + jt + o);
    step(a0, a1, l0, l1, bf, P, Q);
  }

  // ---- cross-wave reduce through LDS (reuse T region) ----
  __syncthreads();                       // all T reads done
  float* R = (float*)T;
  *(f32x4*)&R[wave * 512 + lane * 8]     = P;
  *(f32x4*)&R[wave * 512 + lane * 8 + 4] = Q;
  __syncthreads();

  if (wave == 0) {
    f32x4 Ps = {0.f, 0.f, 0.f, 0.f};
    f32x4 Qs = {0.f, 0.f, 0.f, 0.f};
    #pragma unroll
    for (int w2 = 0; w2 < 8; ++w2) {
      Ps += *(const f32x4*)&R[w2 * 512 + lane * 8];
      Qs += *(const f32x4*)&R[w2 * 512 + lane * 8 + 4];
    }
    // C/D layout: col = lane&15, row = (lane>>4)*4 + reg  [m89]
    float pc[4], qc[4];
    #pragma unroll
    for (int r = 0; r < 4; ++r) {
      pc[r] = __shfl_xor(Ps[r], 8, 64);
      qc[r] = __shfl_xor(Qs[r], 8, 64);
    }
    if (col < 8) {
      const float sc = C_COUPLING / (float)N;
      #pragma unroll
      for (int r = 0; r < 4; ++r) {
        const float sv = __sinf(tl[r]);
        const float cv = __cosf(tl[r]);
        const float coup = sc * (cv * (Ps[r] - qc[r]) - sv * (pc[r] + Qs[r]));
        out[obase + 8 * r] = gv[r] + coup;
      }
    }
  }
}

extern "C" void kernel_launch(void* const* d_in, const int* in_sizes, int n_in,
                              void* d_out, int out_size, void* d_ws, size_t ws_size,
                              hipStream_t stream) {
  const float* theta = (const float*)d_in[0];
  const float* gamma = (const float*)d_in[1];
  const float* aff   = (const float*)d_in[2];
  const float* alp   = (const float*)d_in[3];
  float* out = (float*)d_out;

  const long t0 = in_sizes[0];              // B*N*D (D=8)
  const long t2 = in_sizes[2];              // B*N*N
  const int N = (int)(8 * t2 / t0);
  const int B = (int)(t0 / ((long)N * 8));

  dim3 grid(B * (N / 16));                  // 512 blocks for B=4, N=2048
  vk_fused<<<grid, dim3(512), 0, stream>>>(theta, gamma, aff, alp, out, N);
}

// Round 12
// 31.267 us; speedup vs baseline: 1.0197x; 1.0197x over previous
//
#include <hip/hip_runtime.h>

typedef __attribute__((ext_vector_type(8))) short short8;
typedef __attribute__((ext_vector_type(4))) float f32x4;

#define C_COUPLING 1.0f
#define TPITCH 2056   // shorts per T row: 2048 + 8 pad (4112 B) -> spread banks

// float -> bf16 bits (round-to-nearest-ish; inputs finite, |v|<=1)
__device__ __forceinline__ unsigned short f2bf(float f) {
  unsigned u = __builtin_bit_cast(unsigned, f);
  return (unsigned short)((u + 0x8000u) >> 16);
}

// One block = (b, 16 i-rows). 8 waves = 8 j-chunks of N/8.
// LDS trig table T[c][j] (c<8: sin(theta[b,j,c]); c>=8: cos), full N width.
// P = (A.*cos(alpha)) x [sin|cos], Q = (A.*sin(alpha)) x [sin|cos].
// coupling(i,d) = c_i*(P[d]-Q[d+8]) - s_i*(P[d+8]+Q[d])
// out = gamma + (C/N)*coupling   (theta + DT*ATTR*(gamma-theta) == gamma)
//
// Best-known configuration (R10: 31.1 us). 11 structural variants (R1-R11)
// bracket delivered read BW at ~4.3-4.7 TB/s for this compulsory 134 MB
// once-through stream regardless of MLP/occupancy/addressing -> memory-
// system service-rate wall; single-kernel fusion (no memset, no prep
// kernel, no atomics) is what the structure buys.
__global__ __launch_bounds__(512) void vk_fused(
    const float* __restrict__ theta,
    const float* __restrict__ gamma,
    const float* __restrict__ affinity,
    const float* __restrict__ alpha,
    float* __restrict__ out,
    int N) {
  __shared__ __align__(16) unsigned short T[16 * TPITCH];   // 65792 B

  const int nit = N >> 4;
  const int itile = blockIdx.x % nit;
  const int b = blockIdx.x / nit;
  const int i0 = itile << 4;

  const int tid = threadIdx.x;
  const int wave = tid >> 6, lane = tid & 63;
  const int g = lane >> 4, col = lane & 15;

  // ---- build trig table (4 consecutive j per thread per trip) ----
  {
    const int nj4 = N >> 2;
    for (int j4 = tid; j4 < nj4; j4 += 512) {
      const float* tp = theta + ((size_t)b * N + 4 * (size_t)j4) * 8;
      float v[4][8];
      #pragma unroll
      for (int jj = 0; jj < 4; ++jj) {
        const float4 x = *(const float4*)(tp + jj * 8);
        const float4 y = *(const float4*)(tp + jj * 8 + 4);
        v[jj][0] = x.x; v[jj][1] = x.y; v[jj][2] = x.z; v[jj][3] = x.w;
        v[jj][4] = y.x; v[jj][5] = y.y; v[jj][6] = y.z; v[jj][7] = y.w;
      }
      #pragma unroll
      for (int d = 0; d < 8; ++d) {
        const unsigned s0 = (unsigned)f2bf(__sinf(v[0][d])) |
                            ((unsigned)f2bf(__sinf(v[1][d])) << 16);
        const unsigned s1 = (unsigned)f2bf(__sinf(v[2][d])) |
                            ((unsigned)f2bf(__sinf(v[3][d])) << 16);
        const unsigned c0 = (unsigned)f2bf(__cosf(v[0][d])) |
                            ((unsigned)f2bf(__cosf(v[1][d])) << 16);
        const unsigned c1 = (unsigned)f2bf(__cosf(v[2][d])) |
                            ((unsigned)f2bf(__cosf(v[3][d])) << 16);
        *(uint2*)&T[d * TPITCH + 4 * j4]       = make_uint2(s0, s1);
        *(uint2*)&T[(8 + d) * TPITCH + 4 * j4] = make_uint2(c0, c1);
      }
    }
  }
  __syncthreads();

  // ---- j-loop: wave handles j-chunk [j0, j0 + N/8) ----
  const int jch = N >> 3;
  const int j0 = wave * jch;
  const int o = g * 8;
  const float* __restrict__ Arow =
      affinity + ((size_t)b * N + i0 + col) * (size_t)N + j0;
  const float* __restrict__ Lrow =
      alpha    + ((size_t)b * N + i0 + col) * (size_t)N + j0;
  const unsigned short* Trow = T + col * TPITCH + j0;

  f32x4 P = {0.f, 0.f, 0.f, 0.f};
  f32x4 Q = {0.f, 0.f, 0.f, 0.f};

  #pragma unroll 2
  for (int jt = 0; jt < jch; jt += 32) {
    const float4 a0 = *(const float4*)(Arow + jt + o);
    const float4 a1 = *(const float4*)(Arow + jt + o + 4);
    const float4 l0 = *(const float4*)(Lrow + jt + o);
    const float4 l1 = *(const float4*)(Lrow + jt + o + 4);
    const short8 bf = *(const short8*)(Trow + jt + o);   // LDS b128
    const float av[8] = {a0.x, a0.y, a0.z, a0.w, a1.x, a1.y, a1.z, a1.w};
    const float lv[8] = {l0.x, l0.y, l0.z, l0.w, l1.x, l1.y, l1.z, l1.w};
    short8 wc, ws;
    #pragma unroll
    for (int k = 0; k < 8; ++k) {
      const float sv = __sinf(lv[k]);
      const float cv = __cosf(lv[k]);
      wc[k] = (short)f2bf(av[k] * cv);
      ws[k] = (short)f2bf(av[k] * sv);
    }
    P = __builtin_amdgcn_mfma_f32_16x16x32_bf16(wc, bf, P, 0, 0, 0);
    Q = __builtin_amdgcn_mfma_f32_16x16x32_bf16(ws, bf, Q, 0, 0, 0);
  }

  // ---- cross-wave reduce through LDS (reuse T region) ----
  __syncthreads();                       // all T reads done
  float* R = (float*)T;
  *(f32x4*)&R[wave * 512 + lane * 8]     = P;
  *(f32x4*)&R[wave * 512 + lane * 8 + 4] = Q;
  __syncthreads();

  if (wave == 0) {
    f32x4 Ps = {0.f, 0.f, 0.f, 0.f};
    f32x4 Qs = {0.f, 0.f, 0.f, 0.f};
    #pragma unroll
    for (int w2 = 0; w2 < 8; ++w2) {
      Ps += *(const f32x4*)&R[w2 * 512 + lane * 8];
      Qs += *(const f32x4*)&R[w2 * 512 + lane * 8 + 4];
    }
    // C/D layout: col = lane&15, row = (lane>>4)*4 + reg  [m89]
    float pc[4], qc[4];
    #pragma unroll
    for (int r = 0; r < 4; ++r) {
      pc[r] = __shfl_xor(Ps[r], 8, 64);
      qc[r] = __shfl_xor(Qs[r], 8, 64);
    }
    if (col < 8) {
      const float sc = C_COUPLING / (float)N;
      const size_t obase = (((size_t)b * N + i0 + g * 4) << 3) + col;
      #pragma unroll
      for (int r = 0; r < 4; ++r) {
        const float thi = theta[obase + 8 * r];
        const float sv = __sinf(thi);
        const float cv = __cosf(thi);
        const float coup = sc * (cv * (Ps[r] - qc[r]) - sv * (pc[r] + Qs[r]));
        out[obase + 8 * r] = gamma[obase + 8 * r] + coup;
      }
    }
  }
}

extern "C" void kernel_launch(void* const* d_in, const int* in_sizes, int n_in,
                              void* d_out, int out_size, void* d_ws, size_t ws_size,
                              hipStream_t stream) {
  const float* theta = (const float*)d_in[0];
  const float* gamma = (const float*)d_in[1];
  const float* aff   = (const float*)d_in[2];
  const float* alp   = (const float*)d_in[3];
  float* out = (float*)d_out;

  const long t0 = in_sizes[0];              // B*N*D (D=8)
  const long t2 = in_sizes[2];              // B*N*N
  const int N = (int)(8 * t2 / t0);
  const int B = (int)(t0 / ((long)N * 8));

  dim3 grid(B * (N / 16));                  // 512 blocks for B=4, N=2048
  vk_fused<<<grid, dim3(512), 0, stream>>>(theta, gamma, aff, alp, out, N);
}